// Round 1
// baseline (1143.537 us; speedup 1.0000x reference)
//
#include <hip/hip_runtime.h>

typedef unsigned short u16;
typedef __bf16 bf16x8 __attribute__((ext_vector_type(8)));
typedef float  f32x4  __attribute__((ext_vector_type(4)));

#define B_    128
#define C_    512
#define HW_   196
#define A_    2000
#define T_    20
#define E_    300
#define EP_   320
#define LH_   1024
#define MH_   512
#define NG_   4096   // 4*LH
#define NBLK_ 256    // persistent LSTM grid (1 block/CU)

__device__ __forceinline__ u16 f2b(float f) {
    union { float f; unsigned int u; } v; v.f = f;
    unsigned int u = v.u;
    unsigned int r = u + 0x7fffu + ((u >> 16) & 1u);
    return (u16)(r >> 16);
}
__device__ __forceinline__ float b2f(u16 h) {
    union { unsigned int u; float f; } v; v.u = ((unsigned int)h) << 16;
    return v.f;
}
__device__ __forceinline__ float sigmf(float x) { return 1.f / (1.f + __expf(-x)); }

// ---------------------------------------------------------------------------
// Device-scope grid barrier (sense via monotonic generation counter).
// bar[0] = arrival count, bar[1] = generation. Host memsets to 0 each launch.
// Requires all NBLK_ blocks co-resident: grid=256, 81KB LDS -> 1 block/CU.
// ---------------------------------------------------------------------------
__device__ __forceinline__ void gridbar(int* bar) {
    __syncthreads();
    if (threadIdx.x == 0) {
        __threadfence();   // release: flush this XCD's dirty lines device-wide
        int g = __hip_atomic_load(&bar[1], __ATOMIC_RELAXED, __HIP_MEMORY_SCOPE_AGENT);
        int prev = __hip_atomic_fetch_add(&bar[0], 1, __ATOMIC_ACQ_REL, __HIP_MEMORY_SCOPE_AGENT);
        if (prev == NBLK_ - 1) {
            __hip_atomic_store(&bar[0], 0, __ATOMIC_RELAXED, __HIP_MEMORY_SCOPE_AGENT);
            __hip_atomic_fetch_add(&bar[1], 1, __ATOMIC_RELEASE, __HIP_MEMORY_SCOPE_AGENT);
        } else {
            while (__hip_atomic_load(&bar[1], __ATOMIC_RELAXED, __HIP_MEMORY_SCOPE_AGENT) == g)
                __builtin_amdgcn_s_sleep(2);
        }
        __threadfence();   // acquire: invalidate stale L1/L2 before reading peers' h
    }
    __syncthreads();
}

// ---------------------------------------------------------------------------
// Decode yesno robustly (byte vs int32 packing).
// ---------------------------------------------------------------------------
__global__ void k_decode_yesno(const void* __restrict__ yn_raw, int* __restrict__ yes) {
    __shared__ int bytemode;
    int t = threadIdx.x;
    if (t == 0) bytemode = 0;
    __syncthreads();
    if (t < 32) {
        unsigned int w = ((const unsigned int*)yn_raw)[t];
        if (w > 1u) atomicOr(&bytemode, 1);
    }
    __syncthreads();
    if (t < B_) {
        int v = bytemode ? (int)((const unsigned char*)yn_raw)[t]
                         : ((const int*)yn_raw)[t];
        yes[t] = v ? 1 : 0;
    }
}

// ---------------------------------------------------------------------------
// Find: att = relu(Wsel . features), maps = att0*att1, denom = sum(maps)+1e-6
// ---------------------------------------------------------------------------
__global__ __launch_bounds__(256) void k_find(const float* __restrict__ features,
                                              const int* __restrict__ find_inst,
                                              const float* __restrict__ W_find,
                                              float* __restrict__ maps,
                                              float* __restrict__ denom) {
    __shared__ __align__(16) float w0[C_];
    __shared__ __align__(16) float w1[C_];
    __shared__ float red[256];
    int b = blockIdx.x, t = threadIdx.x;
    int i0 = find_inst[b*2+0], i1 = find_inst[b*2+1];
    w0[t]       = W_find[(size_t)i0*C_ + t];
    w0[t+256]   = W_find[(size_t)i0*C_ + t + 256];
    w1[t]       = W_find[(size_t)i1*C_ + t];
    w1[t+256]   = W_find[(size_t)i1*C_ + t + 256];
    __syncthreads();
    float a0 = 0.f, a1 = 0.f;
    if (t < HW_) {
        const float* f = features + (size_t)b*C_*HW_ + t;
        for (int c = 0; c < C_; c += 4) {
            float4 wv0 = *(const float4*)&w0[c];
            float4 wv1 = *(const float4*)&w1[c];
            float f0 = f[(size_t)c*HW_];
            float f1 = f[(size_t)(c+1)*HW_];
            float f2 = f[(size_t)(c+2)*HW_];
            float f3 = f[(size_t)(c+3)*HW_];
            a0 += wv0.x*f0 + wv0.y*f1 + wv0.z*f2 + wv0.w*f3;
            a1 += wv1.x*f0 + wv1.y*f1 + wv1.z*f2 + wv1.w*f3;
        }
    }
    float m = fmaxf(a0, 0.f) * fmaxf(a1, 0.f);
    if (t < HW_) maps[b*HW_ + t] = m;
    red[t] = (t < HW_) ? m : 0.f;
    __syncthreads();
    for (int s = 128; s > 0; s >>= 1) { if (t < s) red[t] += red[t+s]; __syncthreads(); }
    if (t == 0) denom[b] = red[0] + 1e-6f;
}

// ---------------------------------------------------------------------------
// attended[b,c] = sum_hw (maps/denom) * features
// ---------------------------------------------------------------------------
__global__ __launch_bounds__(256) void k_attended(const float* __restrict__ features,
                                                  const float* __restrict__ maps,
                                                  const float* __restrict__ denom,
                                                  float* __restrict__ attended) {
    __shared__ float ml[HW_];
    int b = blockIdx.x >> 2, cc = blockIdx.x & 3;
    int t = threadIdx.x, wave = t >> 6, lane = t & 63;
    if (t < HW_) ml[t] = maps[b*HW_ + t];
    __syncthreads();
    float dn = denom[b];
    for (int ci = 0; ci < 32; ci++) {
        int c = cc*128 + ci*4 + wave;
        const float* f = features + ((size_t)b*C_ + c)*HW_;
        float p = ml[lane]*f[lane] + ml[lane+64]*f[lane+64] + ml[lane+128]*f[lane+128];
        if (lane < 4) p += ml[192+lane]*f[192+lane];
        for (int off = 32; off > 0; off >>= 1) p += __shfl_down(p, off, 64);
        if (lane == 0) attended[b*C_ + c] = p / dn;
    }
}

// ---------------------------------------------------------------------------
// measure hidden: h = relu(mflat @ W_meas1[r] + b_meas1[r])  (yes samples only)
// ---------------------------------------------------------------------------
__global__ __launch_bounds__(256) void k_meas_h(const int* __restrict__ yes,
                                                const int* __restrict__ root_inst,
                                                const float* __restrict__ maps,
                                                const float* __restrict__ W_meas1,
                                                const float* __restrict__ b_meas1,
                                                float* __restrict__ h_ws) {
    int b = blockIdx.x;
    if (!yes[b]) return;
    __shared__ __align__(16) float mf[HW_];
    int t = threadIdx.x;
    if (t < HW_) mf[t] = maps[b*HW_ + t];
    __syncthreads();
    int r = root_inst[b];
    const float* W = W_meas1 + (size_t)r*HW_*MH_;
    float acc0 = b_meas1[r*MH_ + t];
    float acc1 = b_meas1[r*MH_ + t + 256];
    for (int i = 0; i < HW_; i += 2) {
        float m0 = mf[i], m1 = mf[i+1];
        acc0 += m0*W[(size_t)i*MH_ + t]       + m1*W[(size_t)(i+1)*MH_ + t];
        acc1 += m0*W[(size_t)i*MH_ + t + 256] + m1*W[(size_t)(i+1)*MH_ + t + 256];
    }
    h_ws[b*MH_ + t]       = fmaxf(acc0, 0.f);
    h_ws[b*MH_ + t + 256] = fmaxf(acc1, 0.f);
}

// ---------------------------------------------------------------------------
// yes_logits = h @ W_meas2 + b_meas2   (grid 128*8)
// ---------------------------------------------------------------------------
__global__ __launch_bounds__(256) void k_yes_logits(const int* __restrict__ yes,
                                                    const float* __restrict__ h_ws,
                                                    const float* __restrict__ W_meas2,
                                                    const float* __restrict__ b_meas2,
                                                    float* __restrict__ root_logits) {
    int b = blockIdx.x >> 3, ch = blockIdx.x & 7;
    if (!yes[b]) return;
    __shared__ __align__(16) float h[MH_];
    int t = threadIdx.x;
    h[t]     = h_ws[b*MH_ + t];
    h[t+256] = h_ws[b*MH_ + t + 256];
    __syncthreads();
    int a = ch*256 + t;
    if (a >= A_) return;
    float acc = b_meas2[a];
    for (int k = 0; k < MH_; k += 4) {
        float4 hv = *(const float4*)&h[k];
        acc += hv.x*W_meas2[(size_t)k*A_ + a]     + hv.y*W_meas2[(size_t)(k+1)*A_ + a]
             + hv.z*W_meas2[(size_t)(k+2)*A_ + a] + hv.w*W_meas2[(size_t)(k+3)*A_ + a];
    }
    root_logits[b*A_ + a] = acc;
}

// ---------------------------------------------------------------------------
// other_logits = attended @ W_desc[r] + b_desc[r]   (no samples, grid 128*8)
// ---------------------------------------------------------------------------
__global__ __launch_bounds__(256) void k_other_logits(const int* __restrict__ yes,
                                                      const int* __restrict__ root_inst,
                                                      const float* __restrict__ attended,
                                                      const float* __restrict__ W_desc,
                                                      const float* __restrict__ b_desc,
                                                      float* __restrict__ root_logits) {
    int b = blockIdx.x >> 3, ch = blockIdx.x & 7;
    if (yes[b]) return;
    __shared__ __align__(16) float at[C_];
    int t = threadIdx.x;
    at[t]     = attended[b*C_ + t];
    at[t+256] = attended[b*C_ + t + 256];
    __syncthreads();
    int a = ch*256 + t;
    if (a >= A_) return;
    int r = root_inst[b];
    const float* W = W_desc + (size_t)r*C_*A_;
    float acc = b_desc[r*A_ + a];
    for (int k = 0; k < C_; k += 4) {
        float4 hv = *(const float4*)&at[k];
        acc += hv.x*W[(size_t)k*A_ + a]     + hv.y*W[(size_t)(k+1)*A_ + a]
             + hv.z*W[(size_t)(k+2)*A_ + a] + hv.w*W[(size_t)(k+3)*A_ + a];
    }
    root_logits[b*A_ + a] = acc;
}

// ---------------------------------------------------------------------------
// embedding gather + bf16 cast + K-pad to 320
// ---------------------------------------------------------------------------
__global__ __launch_bounds__(256) void k_embed(const int* __restrict__ question,
                                               const float* __restrict__ E_emb,
                                               u16* __restrict__ Xbf) {
    int gid = blockIdx.x*256 + threadIdx.x;
    if (gid >= B_*T_*EP_) return;
    int row = gid / EP_, k = gid % EP_;
    int q = question[row];
    float v = (k < E_) ? E_emb[(size_t)q*E_ + k] : 0.f;
    Xbf[gid] = f2b(v);
}

// ---------------------------------------------------------------------------
// transpose + bf16 cast: dst[n*K_pad + k] = src[k*N_src + n]  (zero pad)
// ---------------------------------------------------------------------------
__global__ __launch_bounds__(256) void k_transpose_cast(const float* __restrict__ src,
                                                        u16* __restrict__ dst,
                                                        int K_src, int N_src, int K_pad) {
    __shared__ float tile[64][65];
    int kb = blockIdx.x * 64, nb = blockIdx.y * 64;
    int t = threadIdx.x, tc = t & 63, tr = t >> 6;
    for (int rr = 0; rr < 16; rr++) {
        int k = kb + tr + rr*4;
        int n = nb + tc;
        float v = (k < K_src && n < N_src) ? src[(size_t)k*N_src + n] : 0.f;
        tile[tr + rr*4][tc] = v;
    }
    __syncthreads();
    for (int rr = 0; rr < 16; rr++) {
        int n = nb + tr + rr*4;
        dst[(size_t)n*K_pad + kb + tc] = f2b(tile[tc][tr + rr*4]);
    }
}

// ---------------------------------------------------------------------------
// zx = Xbf @ WxT^T + b_lstm   -> bf16 [2560][4096]
// ---------------------------------------------------------------------------
__global__ __launch_bounds__(256) void k_gemm_zx(const u16* __restrict__ Xbf,
                                                 const u16* __restrict__ WxT,
                                                 const float* __restrict__ b_lstm,
                                                 u16* __restrict__ zx) {
    __shared__ __align__(16) u16 As[128][32];
    __shared__ __align__(16) u16 Bs[128][32];
    int bm = blockIdx.x, bn = blockIdx.y;
    int t = threadIdx.x, wave = t >> 6, lane = t & 63;
    int lm = lane & 15, lq = lane >> 4;
    int wr = (wave >> 1) * 64, wc = (wave & 1) * 64;
    f32x4 acc[4][4] = {};
    for (int kc = 0; kc < EP_; kc += 32) {
        for (int s = t; s < 512; s += 256) {
            int row = s >> 2, off = (s & 3) << 3;
            *(int4*)&As[row][off] = *(const int4*)&Xbf[(size_t)(bm*128 + row)*EP_ + kc + off];
            *(int4*)&Bs[row][off] = *(const int4*)&WxT[(size_t)(bn*128 + row)*EP_ + kc + off];
        }
        __syncthreads();
        bf16x8 af[4], bfr[4];
        for (int i = 0; i < 4; i++) af[i]  = *(const bf16x8*)&As[wr + i*16 + lm][lq*8];
        for (int j = 0; j < 4; j++) bfr[j] = *(const bf16x8*)&Bs[wc + j*16 + lm][lq*8];
        for (int i = 0; i < 4; i++)
            for (int j = 0; j < 4; j++)
                acc[i][j] = __builtin_amdgcn_mfma_f32_16x16x32_bf16(af[i], bfr[j], acc[i][j], 0, 0, 0);
        __syncthreads();
    }
    for (int i = 0; i < 4; i++)
        for (int j = 0; j < 4; j++) {
            int col = bn*128 + wc + j*16 + lm;
            float bias = b_lstm[col];
            for (int r = 0; r < 4; r++) {
                int row = bm*128 + wr + i*16 + lq*4 + r;
                zx[(size_t)row*NG_ + col] = f2b(acc[i][j][r] + bias);
            }
        }
}

// ---------------------------------------------------------------------------
// Persistent LSTM: all 20 steps in ONE kernel (grid barrier between steps).
// grid 256 = (2 row-halves) x (128 col-groups of 8 hidden units = 32 gate cols)
// - WhT slice (32 x 1024 bf16, row-padded) resident in LDS for all steps
// - A-fragments read direct global->VGPR (h is L2/LLC resident), fully
//   unrolled K-loop, no barriers inside the GEMM (wave-private A rows)
// - zx gate biases prefetched at step start (issue-early / consume-late)
// - c state lives in LDS for the whole sequence
// ---------------------------------------------------------------------------
__global__ __launch_bounds__(256, 1) void k_lstm_all(const u16* __restrict__ WhT,
                                                     const u16* __restrict__ zx,
                                                     u16* __restrict__ h0,
                                                     u16* __restrict__ h1,
                                                     u16* __restrict__ h_last,
                                                     const int* __restrict__ length,
                                                     int* __restrict__ bar) {
    __shared__ __align__(16) u16 Bs[32][1032];      // +8 u16 pad: conflict-free b128 reads
    __shared__ float Zs[64][33];
    __shared__ __align__(16) u16 Zxs[4][64][8];
    __shared__ float csts[64][8];
    __shared__ int lenS[64];

    int nb = blockIdx.x;
    int mh = nb & 1;            // row half: batches mh*64 .. mh*64+63
    int cg = nb >> 1;           // hidden units j0..j0+7
    int j0 = cg * 8;
    int t = threadIdx.x, wave = t >> 6, lane = t & 63;
    int lm = lane & 15, lq = lane >> 4;

    // stage resident Bs: row c = g*8+jj  <->  WhT row g*1024 + j0 + jj
    for (int i = t; i < 32*128; i += 256) {
        int c = i >> 7, kch = i & 127;
        int g = c >> 3, jj = c & 7;
        *(int4*)&Bs[c][kch*8] = *(const int4*)&WhT[((size_t)(g*1024 + j0 + jj))*LH_ + kch*8];
    }
    if (t < 64) lenS[t] = length[mh*64 + t];
    for (int i = t; i < 512; i += 256) csts[i >> 3][i & 7] = 0.f;
    __syncthreads();

    for (int ts = 0; ts < T_; ts++) {
        const u16* hp = (ts & 1) ? h1 : h0;
        u16*       hw = (ts & 1) ? h0 : h1;

        // prefetch this step's zx slice: thread (wave=g, lane=b) -> 8 bf16
        int4 zxv = *(const int4*)&zx[((size_t)((mh*64 + lane)*T_ + ts))*NG_ + wave*1024 + j0];

        f32x4 acc0 = {}, acc1 = {};
        if (ts > 0) {
            // wave-private A rows: wave w computes rows w*16..w*16+15, all 32 cols
            const u16* arow = hp + (size_t)(mh*64 + wave*16 + lm)*LH_ + lq*8;
            #pragma unroll
            for (int kc = 0; kc < 32; kc++) {
                bf16x8 af  = *(const bf16x8*)(arow + kc*32);
                bf16x8 bf0 = *(const bf16x8*)&Bs[lm][kc*32 + lq*8];
                bf16x8 bf1 = *(const bf16x8*)&Bs[16 + lm][kc*32 + lq*8];
                acc0 = __builtin_amdgcn_mfma_f32_16x16x32_bf16(af, bf0, acc0, 0, 0, 0);
                acc1 = __builtin_amdgcn_mfma_f32_16x16x32_bf16(af, bf1, acc1, 0, 0, 0);
            }
        }

        // park zx prefetch + accumulators in LDS
        *(int4*)&Zxs[wave][lane][0] = zxv;
        #pragma unroll
        for (int r = 0; r < 4; r++) {
            Zs[wave*16 + lq*4 + r][lm]      = acc0[r];
            Zs[wave*16 + lq*4 + r][16 + lm] = acc1[r];
        }
        __syncthreads();

        // gates: 512 (b_loc, jj) pairs
        #pragma unroll
        for (int it = 0; it < 2; it++) {
            int idx = t + it*256;
            int bl = idx >> 3, jj = idx & 7;
            float zi = Zs[bl][jj]      + b2f(Zxs[0][bl][jj]);
            float zf = Zs[bl][8 + jj]  + b2f(Zxs[1][bl][jj]);
            float zg = Zs[bl][16 + jj] + b2f(Zxs[2][bl][jj]);
            float zo = Zs[bl][24 + jj] + b2f(Zxs[3][bl][jj]);
            float cp = csts[bl][jj];
            float cn = sigmf(zf)*cp + sigmf(zi)*tanhf(zg);
            float hn = sigmf(zo)*tanhf(cn);
            csts[bl][jj] = cn;
            u16 hb = f2b(hn);
            int gb = mh*64 + bl;
            hw[(size_t)gb*LH_ + j0 + jj] = hb;
            if (lenS[bl] - 1 == ts) h_last[(size_t)gb*LH_ + j0 + jj] = hb;
        }

        if (ts < T_ - 1) gridbar(bar);   // publish h, sync all 256 blocks
    }
}

// ---------------------------------------------------------------------------
// enc_logits = h_last @ W_enc + b_enc via MFMA; grid 64 blocks (2048/32)
// ---------------------------------------------------------------------------
__global__ __launch_bounds__(256) void k_enc_gemm(const u16* __restrict__ h_last,
                                                  const u16* __restrict__ WencT,
                                                  const float* __restrict__ b_enc,
                                                  float* __restrict__ enc_logits) {
    __shared__ __align__(16) u16 As[128][32];
    __shared__ __align__(16) u16 Bs[32][32];
    __shared__ float Zs[128][32];
    int n0 = blockIdx.x * 32;
    int t = threadIdx.x, wave = t >> 6, lane = t & 63;
    int lm = lane & 15, lq = lane >> 4;
    int wr = wave * 32;
    f32x4 a00 = {}, a01 = {}, a10 = {}, a11 = {};
    for (int kc = 0; kc < LH_; kc += 32) {
        for (int s = t; s < 512; s += 256) {
            int row = s >> 2, off = (s & 3) << 3;
            *(int4*)&As[row][off] = *(const int4*)&h_last[(size_t)row*LH_ + kc + off];
        }
        if (t < 128) {
            int nl = t >> 2, off = (t & 3) << 3;
            *(int4*)&Bs[nl][off] = *(const int4*)&WencT[(size_t)(n0 + nl)*LH_ + kc + off];
        }
        __syncthreads();
        bf16x8 af0 = *(const bf16x8*)&As[wr + lm][lq*8];
        bf16x8 af1 = *(const bf16x8*)&As[wr + 16 + lm][lq*8];
        bf16x8 bf0 = *(const bf16x8*)&Bs[lm][lq*8];
        bf16x8 bf1 = *(const bf16x8*)&Bs[16 + lm][lq*8];
        a00 = __builtin_amdgcn_mfma_f32_16x16x32_bf16(af0, bf0, a00, 0, 0, 0);
        a01 = __builtin_amdgcn_mfma_f32_16x16x32_bf16(af0, bf1, a01, 0, 0, 0);
        a10 = __builtin_amdgcn_mfma_f32_16x16x32_bf16(af1, bf0, a10, 0, 0, 0);
        a11 = __builtin_amdgcn_mfma_f32_16x16x32_bf16(af1, bf1, a11, 0, 0, 0);
        __syncthreads();
    }
    for (int r = 0; r < 4; r++) {
        Zs[wr + lq*4 + r][lm]           = a00[r];
        Zs[wr + lq*4 + r][16 + lm]      = a01[r];
        Zs[wr + 16 + lq*4 + r][lm]      = a10[r];
        Zs[wr + 16 + lq*4 + r][16 + lm] = a11[r];
    }
    __syncthreads();
    for (int it = 0; it < 16; it++) {
        int idx = t + it*256;
        int b = idx >> 5, nl = idx & 31;
        int a = n0 + nl;
        if (a < A_) enc_logits[b*A_ + a] = Zs[b][nl] + b_enc[a];
    }
}

// ---------------------------------------------------------------------------
// final: softmax(root_logits), softmax(enc_logits), out = sqrt(p_r * p_e)
// ---------------------------------------------------------------------------
__global__ __launch_bounds__(256) void k_final(const float* __restrict__ root_logits,
                                               const float* __restrict__ enc_logits,
                                               float* __restrict__ out) {
    __shared__ float red[256];
    int b = blockIdx.x, t = threadIdx.x;
    const float* rl = root_logits + b*A_;
    const float* el = enc_logits + b*A_;
    float m = -1e30f;
    for (int i = t; i < A_; i += 256) m = fmaxf(m, rl[i]);
    red[t] = m; __syncthreads();
    for (int s = 128; s > 0; s >>= 1) { if (t < s) red[t] = fmaxf(red[t], red[t+s]); __syncthreads(); }
    float mr = red[0]; __syncthreads();
    float sum = 0.f;
    for (int i = t; i < A_; i += 256) sum += __expf(rl[i] - mr);
    red[t] = sum; __syncthreads();
    for (int s = 128; s > 0; s >>= 1) { if (t < s) red[t] += red[t+s]; __syncthreads(); }
    float sr = red[0]; __syncthreads();
    m = -1e30f;
    for (int i = t; i < A_; i += 256) m = fmaxf(m, el[i]);
    red[t] = m; __syncthreads();
    for (int s = 128; s > 0; s >>= 1) { if (t < s) red[t] = fmaxf(red[t], red[t+s]); __syncthreads(); }
    float me = red[0]; __syncthreads();
    sum = 0.f;
    for (int i = t; i < A_; i += 256) sum += __expf(el[i] - me);
    red[t] = sum; __syncthreads();
    for (int s = 128; s > 0; s >>= 1) { if (t < s) red[t] += red[t+s]; __syncthreads(); }
    float se = red[0];
    float inv = 1.f / (sr * se);
    for (int i = t; i < A_; i += 256)
        out[b*A_ + i] = sqrtf(__expf(rl[i] - mr) * __expf(el[i] - me) * inv);
}

// ---------------------------------------------------------------------------
extern "C" void kernel_launch(void* const* d_in, const int* in_sizes, int n_in,
                              void* d_out, int out_size, void* d_ws, size_t ws_size,
                              hipStream_t stream) {
    const float* features  = (const float*)d_in[0];
    const int*   question  = (const int*)d_in[1];
    const int*   length    = (const int*)d_in[2];
    const void*  yesno_raw = d_in[3];
    const int*   root_inst = (const int*)d_in[4];
    const int*   find_inst = (const int*)d_in[5];
    const float* W_find    = (const float*)d_in[6];
    const float* W_meas1   = (const float*)d_in[7];
    const float* b_meas1   = (const float*)d_in[8];
    const float* W_meas2   = (const float*)d_in[9];
    const float* b_meas2   = (const float*)d_in[10];
    const float* W_desc    = (const float*)d_in[11];
    const float* b_desc    = (const float*)d_in[12];
    const float* E_emb     = (const float*)d_in[13];
    const float* Wx        = (const float*)d_in[14];
    const float* Wh        = (const float*)d_in[15];
    const float* b_lstm    = (const float*)d_in[16];
    const float* W_enc     = (const float*)d_in[17];
    const float* b_enc     = (const float*)d_in[18];
    float* out = (float*)d_out;

    char* wptr = (char*)d_ws;
    auto take = [&](size_t n) { char* p = wptr; wptr += (n + 255) & ~(size_t)255; return (void*)p; };
    float* maps        = (float*)take((size_t)B_*HW_*4);
    float* denom       = (float*)take((size_t)B_*4);
    float* attended    = (float*)take((size_t)B_*C_*4);
    float* h_meas      = (float*)take((size_t)B_*MH_*4);
    float* root_logits = (float*)take((size_t)B_*A_*4);
    float* enc_logits  = (float*)take((size_t)B_*A_*4);
    int*   yes         = (int*)take((size_t)B_*4);
    u16*   Xbf         = (u16*)take((size_t)B_*T_*EP_*2);
    u16*   WxT         = (u16*)take((size_t)NG_*EP_*2);
    u16*   WhT         = (u16*)take((size_t)NG_*LH_*2);
    u16*   WencT       = (u16*)take((size_t)2048*LH_*2);
    u16*   zx          = (u16*)take((size_t)B_*T_*NG_*2);
    u16*   h0          = (u16*)take((size_t)B_*LH_*2);
    u16*   h1          = (u16*)take((size_t)B_*LH_*2);
    u16*   h_last      = (u16*)take((size_t)B_*LH_*2);
    int*   bar         = (int*)take(256);

    hipMemsetAsync(bar, 0, 256, stream);

    k_decode_yesno<<<1, 128, 0, stream>>>(yesno_raw, yes);

    // module network branch
    k_find<<<128, 256, 0, stream>>>(features, find_inst, W_find, maps, denom);
    k_attended<<<512, 256, 0, stream>>>(features, maps, denom, attended);
    k_meas_h<<<128, 256, 0, stream>>>(yes, root_inst, maps, W_meas1, b_meas1, h_meas);
    k_yes_logits<<<1024, 256, 0, stream>>>(yes, h_meas, W_meas2, b_meas2, root_logits);
    k_other_logits<<<1024, 256, 0, stream>>>(yes, root_inst, attended, W_desc, b_desc, root_logits);

    // LSTM branch
    k_embed<<<(B_*T_*EP_ + 255)/256, 256, 0, stream>>>(question, E_emb, Xbf);
    k_transpose_cast<<<dim3(EP_/64, NG_/64), 256, 0, stream>>>(Wx, WxT, E_, NG_, EP_);
    k_transpose_cast<<<dim3(LH_/64, NG_/64), 256, 0, stream>>>(Wh, WhT, LH_, NG_, LH_);
    k_transpose_cast<<<dim3(LH_/64, 2048/64), 256, 0, stream>>>(W_enc, WencT, LH_, A_, LH_);
    k_gemm_zx<<<dim3((B_*T_)/128, NG_/128), 256, 0, stream>>>(Xbf, WxT, b_lstm, zx);
    k_lstm_all<<<NBLK_, 256, 0, stream>>>(WhT, zx, h0, h1, h_last, length, bar);
    k_enc_gemm<<<64, 256, 0, stream>>>(h_last, WencT, b_enc, enc_logits);

    k_final<<<128, 256, 0, stream>>>(root_logits, enc_logits, out);
}

// Round 2
// 770.164 us; speedup vs baseline: 1.4848x; 1.4848x over previous
//
#include <hip/hip_runtime.h>

typedef unsigned short u16;
typedef unsigned long long u64;
typedef __bf16 bf16x8 __attribute__((ext_vector_type(8)));
typedef float  f32x4  __attribute__((ext_vector_type(4)));
typedef int    i32x4  __attribute__((ext_vector_type(4)));

#define B_    128
#define C_    512
#define HW_   196
#define A_    2000
#define T_    20
#define E_    300
#define EP_   320
#define LH_   1024
#define MH_   512
#define NG_   4096   // 4*LH
#define NLSTM_ 128   // LSTM blocks participating in the grid barrier

__device__ __forceinline__ u16 f2b(float f) {
    union { float f; unsigned int u; } v; v.f = f;
    unsigned int u = v.u;
    unsigned int r = u + 0x7fffu + ((u >> 16) & 1u);
    return (u16)(r >> 16);
}
__device__ __forceinline__ float b2f(u16 h) {
    union { unsigned int u; float f; } v; v.u = ((unsigned int)h) << 16;
    return v.f;
}
__device__ __forceinline__ float sigmf(float x) { return 1.f / (1.f + __expf(-x)); }

// ---------------------------------------------------------------------------
// Fence-free grid barrier for the NLSTM_ LSTM blocks.
// bar[0]: monotonic arrival count (never reset). bar[1]: generation.
// Release ordering: __syncthreads() drains vmcnt(0) => all this block's
// agent-scope h-stores are complete at the LLC before thread 0 arrives.
// All h traffic uses agent-scope relaxed atomics (L2-bypass), so no
// buffer_wbl2 / buffer_inv is ever needed.
// ---------------------------------------------------------------------------
__device__ __forceinline__ void gridbar(int* bar, int target) {
    __syncthreads();
    if (threadIdx.x == 0) {
        int prev = __hip_atomic_fetch_add(&bar[0], 1, __ATOMIC_RELAXED, __HIP_MEMORY_SCOPE_AGENT);
        if (prev == target * NLSTM_ - 1) {
            __hip_atomic_store(&bar[1], target, __ATOMIC_RELAXED, __HIP_MEMORY_SCOPE_AGENT);
        } else {
            while (__hip_atomic_load(&bar[1], __ATOMIC_RELAXED, __HIP_MEMORY_SCOPE_AGENT) < target)
                __builtin_amdgcn_s_sleep(1);
        }
    }
    __syncthreads();
}

// ---------------------------------------------------------------------------
// embedding gather + bf16 cast + K-pad to 320
// ---------------------------------------------------------------------------
__global__ __launch_bounds__(256) void k_embed(const int* __restrict__ question,
                                               const float* __restrict__ E_emb,
                                               u16* __restrict__ Xbf) {
    int gid = blockIdx.x*256 + threadIdx.x;
    if (gid >= B_*T_*EP_) return;
    int row = gid / EP_, k = gid % EP_;
    int q = question[row];
    float v = (k < E_) ? E_emb[(size_t)q*E_ + k] : 0.f;
    Xbf[gid] = f2b(v);
}

// ---------------------------------------------------------------------------
// transpose + bf16 cast: dst[n*K_pad + k] = src[k*N_src + n]  (zero pad)
// ---------------------------------------------------------------------------
__global__ __launch_bounds__(256) void k_transpose_cast(const float* __restrict__ src,
                                                        u16* __restrict__ dst,
                                                        int K_src, int N_src, int K_pad) {
    __shared__ float tile[64][65];
    int kb = blockIdx.x * 64, nb = blockIdx.y * 64;
    int t = threadIdx.x, tc = t & 63, tr = t >> 6;
    for (int rr = 0; rr < 16; rr++) {
        int k = kb + tr + rr*4;
        int n = nb + tc;
        float v = (k < K_src && n < N_src) ? src[(size_t)k*N_src + n] : 0.f;
        tile[tr + rr*4][tc] = v;
    }
    __syncthreads();
    for (int rr = 0; rr < 16; rr++) {
        int n = nb + tr + rr*4;
        dst[(size_t)n*K_pad + kb + tc] = f2b(tile[tc][tr + rr*4]);
    }
}

// ---------------------------------------------------------------------------
// zx = Xbf @ WxT^T + b_lstm   -> bf16 [2560][4096]
// ---------------------------------------------------------------------------
__global__ __launch_bounds__(256) void k_gemm_zx(const u16* __restrict__ Xbf,
                                                 const u16* __restrict__ WxT,
                                                 const float* __restrict__ b_lstm,
                                                 u16* __restrict__ zx) {
    __shared__ __align__(16) u16 As[128][32];
    __shared__ __align__(16) u16 Bs[128][32];
    int bm = blockIdx.x, bn = blockIdx.y;
    int t = threadIdx.x, wave = t >> 6, lane = t & 63;
    int lm = lane & 15, lq = lane >> 4;
    int wr = (wave >> 1) * 64, wc = (wave & 1) * 64;
    f32x4 acc[4][4] = {};
    for (int kc = 0; kc < EP_; kc += 32) {
        for (int s = t; s < 512; s += 256) {
            int row = s >> 2, off = (s & 3) << 3;
            *(int4*)&As[row][off] = *(const int4*)&Xbf[(size_t)(bm*128 + row)*EP_ + kc + off];
            *(int4*)&Bs[row][off] = *(const int4*)&WxT[(size_t)(bn*128 + row)*EP_ + kc + off];
        }
        __syncthreads();
        bf16x8 af[4], bfr[4];
        for (int i = 0; i < 4; i++) af[i]  = *(const bf16x8*)&As[wr + i*16 + lm][lq*8];
        for (int j = 0; j < 4; j++) bfr[j] = *(const bf16x8*)&Bs[wc + j*16 + lm][lq*8];
        for (int i = 0; i < 4; i++)
            for (int j = 0; j < 4; j++)
                acc[i][j] = __builtin_amdgcn_mfma_f32_16x16x32_bf16(af[i], bfr[j], acc[i][j], 0, 0, 0);
        __syncthreads();
    }
    for (int i = 0; i < 4; i++)
        for (int j = 0; j < 4; j++) {
            int col = bn*128 + wc + j*16 + lm;
            float bias = b_lstm[col];
            for (int r = 0; r < 4; r++) {
                int row = bm*128 + wr + i*16 + lq*4 + r;
                zx[(size_t)row*NG_ + col] = f2b(acc[i][j][r] + bias);
            }
        }
}

// ---------------------------------------------------------------------------
// MEGA kernel, grid 256 (all CUs, 1 block/CU forced by LDS):
//   blocks 0..127   : persistent LSTM (fence-free barrier among themselves)
//                     block = (batch half mh) x (16 hidden units j0..j0+15)
//                     Wh slice (64 gate-cols x 1024) LDS-resident all 20 steps
//   blocks 128..255 : per-sample module network (decode/find/attended or
//                     meas_h, then 512->2000 matvec) -- fully overlapped
// ---------------------------------------------------------------------------
__global__ __launch_bounds__(256, 1) void k_mega(
    const u16* __restrict__ WhT, const u16* __restrict__ zx,
    u16* __restrict__ h0, u16* __restrict__ h1, u16* __restrict__ h_last,
    const int* __restrict__ length, int* __restrict__ bar,
    const void* __restrict__ yn_raw, const int* __restrict__ root_inst,
    const int* __restrict__ find_inst, const float* __restrict__ features,
    const float* __restrict__ W_find,
    const float* __restrict__ W_meas1, const float* __restrict__ b_meas1,
    const float* __restrict__ W_meas2, const float* __restrict__ b_meas2,
    const float* __restrict__ W_desc,  const float* __restrict__ b_desc,
    float* __restrict__ root_logits)
{
    __shared__ __align__(16) char smem[161280];
    const int blk = blockIdx.x;
    const int t = threadIdx.x;

    if (blk < NLSTM_) {
        // ================= LSTM path =================
        const int mh = blk & 1;             // batch half: rows mh*64..mh*64+63
        const int j0 = (blk >> 1) * 16;     // hidden units j0..j0+15
        const int wave = t >> 6, lane = t & 63, lm = lane & 15, lq = lane >> 4;

        u16*   Bs   = (u16*)smem;                    // [64][1032] (stride 2064B: conflict-free)
        float* Zs   = (float*)(smem + 132096);       // [64][65]
        u16*   Zxs  = (u16*)(smem + 148736);         // [64][64]  (batch x gatecol)
        float* csts = (float*)(smem + 156928);       // [64*16]
        int*   lenS = (int*)(smem + 161024);         // [64]

        // stage Wh slice once: Bs row c = g*16+u  <->  WhT row g*1024 + j0 + u
        for (int i = t; i < 8192; i += 256) {
            int c = i >> 7, kch = i & 127;
            int g = c >> 4, u = c & 15;
            *(int4*)&Bs[(size_t)c*1032 + kch*8] =
                *(const int4*)&WhT[((size_t)(g*1024 + j0 + u))*LH_ + kch*8];
        }
        if (t < 64) lenS[t] = length[mh*64 + t];
        for (int i = t; i < 1024; i += 256) csts[i] = 0.f;
        __syncthreads();

        // ---- step 0: h_prev = 0 -> z = zx only ----
        {
            #pragma unroll
            for (int it = 0; it < 2; ++it) {
                int idx = t + it*256;
                int bl = idx >> 3, u0 = (idx & 7) * 2;
                const u16* zr = zx + (size_t)(mh*64 + bl)*T_*NG_ + j0;  // ts=0
                float zi0 = b2f(zr[u0]),        zi1 = b2f(zr[u0+1]);
                float zf0 = b2f(zr[1024+u0]),   zf1 = b2f(zr[1024+u0+1]);
                float zg0 = b2f(zr[2048+u0]),   zg1 = b2f(zr[2048+u0+1]);
                float zo0 = b2f(zr[3072+u0]),   zo1 = b2f(zr[3072+u0+1]);
                float cn0 = sigmf(zf0)*0.f + sigmf(zi0)*tanhf(zg0);
                float cn1 = sigmf(zf1)*0.f + sigmf(zi1)*tanhf(zg1);
                float hn0 = sigmf(zo0)*tanhf(cn0);
                float hn1 = sigmf(zo1)*tanhf(cn1);
                csts[bl*16 + u0]     = cn0;
                csts[bl*16 + u0 + 1] = cn1;
                unsigned pack = (unsigned)f2b(hn0) | ((unsigned)f2b(hn1) << 16);
                int gb = mh*64 + bl;
                __hip_atomic_store((unsigned*)(h1 + (size_t)gb*LH_ + j0 + u0), pack,
                                   __ATOMIC_RELAXED, __HIP_MEMORY_SCOPE_AGENT);
                if (lenS[bl] == 1) *(unsigned*)(h_last + (size_t)gb*LH_ + j0 + u0) = pack;
            }
            gridbar(bar, 1);
        }

        // ---- steps 1..19 ----
        for (int ts = 1; ts < T_; ++ts) {
            const u16* hp = (ts & 1) ? h1 : h0;
            u16*       hw = (ts & 1) ? h0 : h1;

            // zx prefetch for this step: thread -> (batch t>>2, gate t&3), 16 units
            const i32x4* zp = (const i32x4*)(zx + ((size_t)((mh*64 + (t>>2))*T_ + ts))*NG_
                                             + (size_t)(t&3)*1024 + j0);
            i32x4 zq0 = zp[0], zq1 = zp[1];

            // A-fragments: issue all 64 agent-scope (LLC-coherent) loads first
            u64 aq[64];
            u64* ap = (u64*)(hp + (size_t)(mh*64 + wave*16 + lm)*LH_);
            #pragma unroll
            for (int kc = 0; kc < 32; ++kc) {
                aq[2*kc]   = __hip_atomic_load(ap + kc*8 + lq*2,     __ATOMIC_RELAXED, __HIP_MEMORY_SCOPE_AGENT);
                aq[2*kc+1] = __hip_atomic_load(ap + kc*8 + lq*2 + 1, __ATOMIC_RELAXED, __HIP_MEMORY_SCOPE_AGENT);
            }

            f32x4 ac0 = {}, ac1 = {}, ac2 = {}, ac3 = {};
            const char* bsb = (const char*)Bs + (size_t)lm*2064 + lq*16;
            #pragma unroll
            for (int kc = 0; kc < 32; ++kc) {
                union { u64 q[2]; bf16x8 v; } ua;
                ua.q[0] = aq[2*kc]; ua.q[1] = aq[2*kc+1];
                bf16x8 b0 = *(const bf16x8*)(bsb + 0*33024 + kc*64);
                bf16x8 b1 = *(const bf16x8*)(bsb + 1*33024 + kc*64);
                bf16x8 b2 = *(const bf16x8*)(bsb + 2*33024 + kc*64);
                bf16x8 b3 = *(const bf16x8*)(bsb + 3*33024 + kc*64);
                ac0 = __builtin_amdgcn_mfma_f32_16x16x32_bf16(ua.v, b0, ac0, 0, 0, 0);
                ac1 = __builtin_amdgcn_mfma_f32_16x16x32_bf16(ua.v, b1, ac1, 0, 0, 0);
                ac2 = __builtin_amdgcn_mfma_f32_16x16x32_bf16(ua.v, b2, ac2, 0, 0, 0);
                ac3 = __builtin_amdgcn_mfma_f32_16x16x32_bf16(ua.v, b3, ac3, 0, 0, 0);
            }

            // park zx + accumulators in LDS
            *(i32x4*)&Zxs[(size_t)(t>>2)*64 + (t&3)*16]     = zq0;
            *(i32x4*)&Zxs[(size_t)(t>>2)*64 + (t&3)*16 + 8] = zq1;
            #pragma unroll
            for (int r = 0; r < 4; ++r) {
                float* zr = Zs + (size_t)(wave*16 + lq*4 + r)*65;
                zr[lm]      = ac0[r];
                zr[16+lm]   = ac1[r];
                zr[32+lm]   = ac2[r];
                zr[48+lm]   = ac3[r];
            }
            __syncthreads();

            // gates: 512 (batch, unit-pair) items over 2 iterations
            #pragma unroll
            for (int it = 0; it < 2; ++it) {
                int idx = t + it*256;
                int bl = idx >> 3, u0 = (idx & 7) * 2;
                float* zrow = Zs + (size_t)bl*65;
                u16*   zxr  = Zxs + (size_t)bl*64;
                float zi0 = zrow[u0]      + b2f(zxr[u0]);
                float zf0 = zrow[16+u0]   + b2f(zxr[16+u0]);
                float zg0 = zrow[32+u0]   + b2f(zxr[32+u0]);
                float zo0 = zrow[48+u0]   + b2f(zxr[48+u0]);
                float zi1 = zrow[u0+1]    + b2f(zxr[u0+1]);
                float zf1 = zrow[16+u0+1] + b2f(zxr[16+u0+1]);
                float zg1 = zrow[32+u0+1] + b2f(zxr[32+u0+1]);
                float zo1 = zrow[48+u0+1] + b2f(zxr[48+u0+1]);
                float cp0 = csts[bl*16 + u0], cp1 = csts[bl*16 + u0 + 1];
                float cn0 = sigmf(zf0)*cp0 + sigmf(zi0)*tanhf(zg0);
                float cn1 = sigmf(zf1)*cp1 + sigmf(zi1)*tanhf(zg1);
                float hn0 = sigmf(zo0)*tanhf(cn0);
                float hn1 = sigmf(zo1)*tanhf(cn1);
                csts[bl*16 + u0]     = cn0;
                csts[bl*16 + u0 + 1] = cn1;
                unsigned pack = (unsigned)f2b(hn0) | ((unsigned)f2b(hn1) << 16);
                int gb = mh*64 + bl;
                __hip_atomic_store((unsigned*)(hw + (size_t)gb*LH_ + j0 + u0), pack,
                                   __ATOMIC_RELAXED, __HIP_MEMORY_SCOPE_AGENT);
                if (lenS[bl] - 1 == ts) *(unsigned*)(h_last + (size_t)gb*LH_ + j0 + u0) = pack;
            }

            if (ts < T_ - 1) gridbar(bar, ts + 1);
        }
    } else {
        // ================= module-network path: one sample per block =================
        const int b = blk - NLSTM_;
        float* base  = (float*)smem;
        float* w0    = base;          // 512
        float* w1    = base + 512;    // 512
        float* redS  = base + 1024;   // 256
        float* mapsS = base + 1280;   // 256 (196 used)
        float* xS    = base + 1536;   // 512
        float* miscS = base + 2048;   // [0]=denom, [1]=yes flag

        if (t == 0) {
            // robust yesno decode: byte- vs int32-packed
            int bm = 0;
            const unsigned* yw = (const unsigned*)yn_raw;
            for (int i = 0; i < 32; i++) if (yw[i] > 1u) bm = 1;
            int v = bm ? (int)((const unsigned char*)yn_raw)[b] : ((const int*)yn_raw)[b];
            miscS[1] = v ? 1.f : 0.f;
        }

        int i0 = find_inst[b*2+0], i1 = find_inst[b*2+1];
        w0[t]     = W_find[(size_t)i0*C_ + t];
        w0[t+256] = W_find[(size_t)i0*C_ + t + 256];
        w1[t]     = W_find[(size_t)i1*C_ + t];
        w1[t+256] = W_find[(size_t)i1*C_ + t + 256];
        __syncthreads();

        float a0 = 0.f, a1 = 0.f;
        if (t < HW_) {
            const float* f = features + (size_t)b*C_*HW_ + t;
            for (int c = 0; c < C_; c += 4) {
                float4 wv0 = *(const float4*)&w0[c];
                float4 wv1 = *(const float4*)&w1[c];
                float f0 = f[(size_t)c*HW_];
                float f1 = f[(size_t)(c+1)*HW_];
                float f2 = f[(size_t)(c+2)*HW_];
                float f3 = f[(size_t)(c+3)*HW_];
                a0 += wv0.x*f0 + wv0.y*f1 + wv0.z*f2 + wv0.w*f3;
                a1 += wv1.x*f0 + wv1.y*f1 + wv1.z*f2 + wv1.w*f3;
            }
        }
        float m = fmaxf(a0, 0.f) * fmaxf(a1, 0.f);
        if (t < HW_) mapsS[t] = m;
        redS[t] = (t < HW_) ? m : 0.f;
        __syncthreads();
        for (int s = 128; s > 0; s >>= 1) { if (t < s) redS[t] += redS[t+s]; __syncthreads(); }
        if (t == 0) miscS[0] = redS[0] + 1e-6f;
        __syncthreads();

        const int yes_b = (miscS[1] != 0.f);
        const int r = root_inst[b];

        if (yes_b) {
            // measure hidden: xS = relu(mflat @ W_meas1[r] + b_meas1[r])
            const float* W = W_meas1 + (size_t)r*HW_*MH_;
            float acc0 = b_meas1[r*MH_ + t];
            float acc1 = b_meas1[r*MH_ + t + 256];
            for (int i = 0; i < HW_; i += 2) {
                float m0 = mapsS[i], m1 = mapsS[i+1];
                acc0 += m0*W[(size_t)i*MH_ + t]       + m1*W[(size_t)(i+1)*MH_ + t];
                acc1 += m0*W[(size_t)i*MH_ + t + 256] + m1*W[(size_t)(i+1)*MH_ + t + 256];
            }
            xS[t]     = fmaxf(acc0, 0.f);
            xS[t+256] = fmaxf(acc1, 0.f);
        } else {
            // attended: xS[c] = sum_hw (maps/denom) * features  (wave per channel)
            int wave = t >> 6, lane = t & 63;
            float dn = miscS[0];
            for (int ci = 0; ci < 128; ci++) {
                int c = wave*128 + ci;
                const float* f = features + ((size_t)b*C_ + c)*HW_;
                float p = mapsS[lane]*f[lane] + mapsS[lane+64]*f[lane+64] + mapsS[lane+128]*f[lane+128];
                if (lane < 4) p += mapsS[192+lane]*f[192+lane];
                for (int off = 32; off > 0; off >>= 1) p += __shfl_down(p, off, 64);
                if (lane == 0) xS[c] = p / dn;
            }
        }
        __syncthreads();

        // logits = xS @ W2 + bias  (K=512, N=2000)
        const float* W2 = yes_b ? W_meas2 : (W_desc + (size_t)r*C_*A_);
        const float* bb = yes_b ? b_meas2 : (b_desc + (size_t)r*A_);
        for (int i = 0; i < 8; i++) {
            int a = t + i*256;
            if (a < A_) {
                float acc = bb[a];
                for (int k = 0; k < 512; k += 4) {
                    float4 xv = *(const float4*)&xS[k];
                    acc += xv.x*W2[(size_t)k*A_ + a]     + xv.y*W2[(size_t)(k+1)*A_ + a]
                         + xv.z*W2[(size_t)(k+2)*A_ + a] + xv.w*W2[(size_t)(k+3)*A_ + a];
                }
                root_logits[(size_t)b*A_ + a] = acc;
            }
        }
    }
}

// ---------------------------------------------------------------------------
// enc_logits = h_last @ W_enc + b_enc via MFMA; grid 64 blocks (2048/32)
// ---------------------------------------------------------------------------
__global__ __launch_bounds__(256) void k_enc_gemm(const u16* __restrict__ h_last,
                                                  const u16* __restrict__ WencT,
                                                  const float* __restrict__ b_enc,
                                                  float* __restrict__ enc_logits) {
    __shared__ __align__(16) u16 As[128][32];
    __shared__ __align__(16) u16 Bs[32][32];
    __shared__ float Zs[128][32];
    int n0 = blockIdx.x * 32;
    int t = threadIdx.x, wave = t >> 6, lane = t & 63;
    int lm = lane & 15, lq = lane >> 4;
    int wr = wave * 32;
    f32x4 a00 = {}, a01 = {}, a10 = {}, a11 = {};
    for (int kc = 0; kc < LH_; kc += 32) {
        for (int s = t; s < 512; s += 256) {
            int row = s >> 2, off = (s & 3) << 3;
            *(int4*)&As[row][off] = *(const int4*)&h_last[(size_t)row*LH_ + kc + off];
        }
        if (t < 128) {
            int nl = t >> 2, off = (t & 3) << 3;
            *(int4*)&Bs[nl][off] = *(const int4*)&WencT[(size_t)(n0 + nl)*LH_ + kc + off];
        }
        __syncthreads();
        bf16x8 af0 = *(const bf16x8*)&As[wr + lm][lq*8];
        bf16x8 af1 = *(const bf16x8*)&As[wr + 16 + lm][lq*8];
        bf16x8 bf0 = *(const bf16x8*)&Bs[lm][lq*8];
        bf16x8 bf1 = *(const bf16x8*)&Bs[16 + lm][lq*8];
        a00 = __builtin_amdgcn_mfma_f32_16x16x32_bf16(af0, bf0, a00, 0, 0, 0);
        a01 = __builtin_amdgcn_mfma_f32_16x16x32_bf16(af0, bf1, a01, 0, 0, 0);
        a10 = __builtin_amdgcn_mfma_f32_16x16x32_bf16(af1, bf0, a10, 0, 0, 0);
        a11 = __builtin_amdgcn_mfma_f32_16x16x32_bf16(af1, bf1, a11, 0, 0, 0);
        __syncthreads();
    }
    for (int r = 0; r < 4; r++) {
        Zs[wr + lq*4 + r][lm]           = a00[r];
        Zs[wr + lq*4 + r][16 + lm]      = a01[r];
        Zs[wr + 16 + lq*4 + r][lm]      = a10[r];
        Zs[wr + 16 + lq*4 + r][16 + lm] = a11[r];
    }
    __syncthreads();
    for (int it = 0; it < 16; it++) {
        int idx = t + it*256;
        int b = idx >> 5, nl = idx & 31;
        int a = n0 + nl;
        if (a < A_) enc_logits[b*A_ + a] = Zs[b][nl] + b_enc[a];
    }
}

// ---------------------------------------------------------------------------
// final: softmax(root_logits), softmax(enc_logits), out = sqrt(p_r * p_e)
// ---------------------------------------------------------------------------
__global__ __launch_bounds__(256) void k_final(const float* __restrict__ root_logits,
                                               const float* __restrict__ enc_logits,
                                               float* __restrict__ out) {
    __shared__ float red[256];
    int b = blockIdx.x, t = threadIdx.x;
    const float* rl = root_logits + b*A_;
    const float* el = enc_logits + b*A_;
    float m = -1e30f;
    for (int i = t; i < A_; i += 256) m = fmaxf(m, rl[i]);
    red[t] = m; __syncthreads();
    for (int s = 128; s > 0; s >>= 1) { if (t < s) red[t] = fmaxf(red[t], red[t+s]); __syncthreads(); }
    float mr = red[0]; __syncthreads();
    float sum = 0.f;
    for (int i = t; i < A_; i += 256) sum += __expf(rl[i] - mr);
    red[t] = sum; __syncthreads();
    for (int s = 128; s > 0; s >>= 1) { if (t < s) red[t] += red[t+s]; __syncthreads(); }
    float sr = red[0]; __syncthreads();
    m = -1e30f;
    for (int i = t; i < A_; i += 256) m = fmaxf(m, el[i]);
    red[t] = m; __syncthreads();
    for (int s = 128; s > 0; s >>= 1) { if (t < s) red[t] = fmaxf(red[t], red[t+s]); __syncthreads(); }
    float me = red[0]; __syncthreads();
    sum = 0.f;
    for (int i = t; i < A_; i += 256) sum += __expf(el[i] - me);
    red[t] = sum; __syncthreads();
    for (int s = 128; s > 0; s >>= 1) { if (t < s) red[t] += red[t+s]; __syncthreads(); }
    float se = red[0];
    float inv = 1.f / (sr * se);
    for (int i = t; i < A_; i += 256)
        out[b*A_ + i] = sqrtf(__expf(rl[i] - mr) * __expf(el[i] - me) * inv);
}

// ---------------------------------------------------------------------------
extern "C" void kernel_launch(void* const* d_in, const int* in_sizes, int n_in,
                              void* d_out, int out_size, void* d_ws, size_t ws_size,
                              hipStream_t stream) {
    const float* features  = (const float*)d_in[0];
    const int*   question  = (const int*)d_in[1];
    const int*   length    = (const int*)d_in[2];
    const void*  yesno_raw = d_in[3];
    const int*   root_inst = (const int*)d_in[4];
    const int*   find_inst = (const int*)d_in[5];
    const float* W_find    = (const float*)d_in[6];
    const float* W_meas1   = (const float*)d_in[7];
    const float* b_meas1   = (const float*)d_in[8];
    const float* W_meas2   = (const float*)d_in[9];
    const float* b_meas2   = (const float*)d_in[10];
    const float* W_desc    = (const float*)d_in[11];
    const float* b_desc    = (const float*)d_in[12];
    const float* E_emb     = (const float*)d_in[13];
    const float* Wx        = (const float*)d_in[14];
    const float* Wh        = (const float*)d_in[15];
    const float* b_lstm    = (const float*)d_in[16];
    const float* W_enc     = (const float*)d_in[17];
    const float* b_enc     = (const float*)d_in[18];
    float* out = (float*)d_out;

    char* wptr = (char*)d_ws;
    auto take = [&](size_t n) { char* p = wptr; wptr += (n + 255) & ~(size_t)255; return (void*)p; };
    float* root_logits = (float*)take((size_t)B_*A_*4);
    float* enc_logits  = (float*)take((size_t)B_*A_*4);
    u16*   Xbf         = (u16*)take((size_t)B_*T_*EP_*2);
    u16*   WxT         = (u16*)take((size_t)NG_*EP_*2);
    u16*   WhT         = (u16*)take((size_t)NG_*LH_*2);
    u16*   WencT       = (u16*)take((size_t)2048*LH_*2);
    u16*   zx          = (u16*)take((size_t)B_*T_*NG_*2);
    u16*   h0          = (u16*)take((size_t)B_*LH_*2);
    u16*   h1          = (u16*)take((size_t)B_*LH_*2);
    u16*   h_last      = (u16*)take((size_t)B_*LH_*2);
    int*   bar         = (int*)take(256);

    hipMemsetAsync(bar, 0, 256, stream);

    // LSTM preprocessing
    k_embed<<<(B_*T_*EP_ + 255)/256, 256, 0, stream>>>(question, E_emb, Xbf);
    k_transpose_cast<<<dim3(EP_/64, NG_/64), 256, 0, stream>>>(Wx, WxT, E_, NG_, EP_);
    k_transpose_cast<<<dim3(LH_/64, NG_/64), 256, 0, stream>>>(Wh, WhT, LH_, NG_, LH_);
    k_transpose_cast<<<dim3(LH_/64, 2048/64), 256, 0, stream>>>(W_enc, WencT, LH_, A_, LH_);
    k_gemm_zx<<<dim3((B_*T_)/128, NG_/128), 256, 0, stream>>>(Xbf, WxT, b_lstm, zx);

    // persistent LSTM || module network
    k_mega<<<256, 256, 0, stream>>>(WhT, zx, h0, h1, h_last, length, bar,
                                    yesno_raw, root_inst, find_inst, features, W_find,
                                    W_meas1, b_meas1, W_meas2, b_meas2, W_desc, b_desc,
                                    root_logits);

    k_enc_gemm<<<64, 256, 0, stream>>>(h_last, WencT, b_enc, enc_logits);
    k_final<<<128, 256, 0, stream>>>(root_logits, enc_logits, out);
}